// Round 6
// baseline (282.546 us; speedup 1.0000x reference)
//
#include <hip/hip_runtime.h>

// DirectionalProcessor: out[b,y,x,o] = bc[o] + sum_{d,c} g[b,y-dy_d,x-dx_d,c] * M_d[c,o]
// with M_d[c,o] = sum_e Wd[d,c,e]*Wc[o,d*256+e]  (folded -> 68.7 GFLOP implicit GEMM
// [65536 x 2048] @ [2048 x 256], B,H,W,C=16,64,64,256, 8 dirs).
//
// R10: fuse pad_convert INTO conv. Across R0..R9, total - conv ~= 120 us constant:
// the gp round-trip (write 71 MB bf16 + re-read) + 3 launches was the tail wagging
// the dog. conv now reg-stages the 6x66x32ch halo slab directly from f32 g
// (issue-early/write-late: batch1 at body start, batch2 mid-stage; convert+ds_write
// at stage end), same swizzled slab layout as R9 so readAh is unchanged. Zero-pad
// is a per-chunk boundary predicate. No global_load_lds -> no manual vmcnt ledger:
// compiler's per-register vmcnt covers staged loads (at pack, newer outstanding =
// 16 B-loads -> it emits vmcnt(16), keeping all B prefetches flying). Manual sync
// is just lgkmcnt(0)+s_barrier per stage. 2 slabs (write lands in-stage, one
// barrier before read), LDS 50.7 KB. pad_convert kernel + 35.7 MB gp workspace
// deleted; 2 dispatches total. build_mt scatter packed into ushort4 (4x fewer
// stores).

typedef unsigned short u16;
typedef unsigned int u32;
typedef __attribute__((ext_vector_type(8))) short bf16x8;   // 8 x bf16 = 4 VGPRs
typedef __attribute__((ext_vector_type(4))) float f32x4;

__device__ __forceinline__ u16 f2bf(float f) {   // RNE f32->bf16
  u32 u = __float_as_uint(f);
  u32 r = u + 0x7fffu + ((u >> 16) & 1u);
  return (u16)(r >> 16);
}
__device__ __forceinline__ u32 pack2(float a, float b) {
  return (u32)f2bf(a) | ((u32)f2bf(b) << 16);
}

// ---------------- kernel 1: MFMA weight fold into fragment-ordered Bf ----------------
// Bf u16 index: ((d*8 + c32)*16 + o16)*512 + lane*8 + e, where lane = (o&15) + ((c>>3)&3)*16
// holds M_d[c = c32*32 + (lane>>4)*8 + e][o = o16*16 + (lane&15)]  (B-operand frag order).
__global__ __launch_bounds__(256) void build_mt(const float* __restrict__ Wd,
                                                const float* __restrict__ Wc,
                                                u16* __restrict__ Bf) {
  __shared__ __align__(16) u16 As[128 * 32];
  __shared__ __align__(16) u16 Bs[128 * 32];
  const int bid = blockIdx.x;          // 32 blocks: 2 n-tiles x (8 d x 2 c-halves)
  const int n0    = (bid & 1) << 7;
  const int mblk  = bid >> 1;          // 0..15
  const int d     = mblk >> 1;
  const int chalf = (mblk & 1) << 7;
  const int tid  = threadIdx.x;
  const int lane = tid & 63, wid = tid >> 6;
  const int wm = (wid >> 1) << 6, wn = (wid & 1) << 6;
  const int quad = lane >> 4, r16 = lane & 15;
  const int srow = tid >> 1, hh = tid & 1;
  const int swz  = (srow >> 1) & 3;
  const int ssl  = (quad ^ ((r16 >> 1) & 3)) << 3;
  f32x4 acc[4][4] = {};

  for (int e0 = 0; e0 < 256; e0 += 32) {
    __syncthreads();
    const float* pa = Wd + (size_t)(d * 256 + chalf + srow) * 256 + e0 + hh * 16;
    const float* pb = Wc + (size_t)(n0 + srow) * 2048 + d * 256 + e0 + hh * 16;
#pragma unroll
    for (int i = 0; i < 2; ++i) {
      float4 a0 = *(const float4*)(pa + i * 8);
      float4 a1 = *(const float4*)(pa + i * 8 + 4);
      float4 b0 = *(const float4*)(pb + i * 8);
      float4 b1 = *(const float4*)(pb + i * 8 + 4);
      uint4 va, vb;
      va.x = pack2(a0.x, a0.y); va.y = pack2(a0.z, a0.w);
      va.z = pack2(a1.x, a1.y); va.w = pack2(a1.z, a1.w);
      vb.x = pack2(b0.x, b0.y); vb.y = pack2(b0.z, b0.w);
      vb.z = pack2(b1.x, b1.y); vb.w = pack2(b1.z, b1.w);
      int slot = (2 * hh + i) ^ swz;
      *(uint4*)&As[srow * 32 + slot * 8] = va;
      *(uint4*)&Bs[srow * 32 + slot * 8] = vb;
    }
    __syncthreads();
    bf16x8 bfr[4];
#pragma unroll
    for (int nt = 0; nt < 4; ++nt)
      bfr[nt] = *(const bf16x8*)&Bs[(wn + nt * 16 + r16) * 32 + ssl];
#pragma unroll
    for (int mt = 0; mt < 4; ++mt) {
      bf16x8 af = *(const bf16x8*)&As[(wm + mt * 16 + r16) * 32 + ssl];
#pragma unroll
      for (int nt = 0; nt < 4; ++nt)
        acc[mt][nt] = __builtin_amdgcn_mfma_f32_16x16x32_bf16(af, bfr[nt], acc[mt][nt], 0, 0, 0);
    }
  }
  // scatter into fragment-ordered Bf (C/D layout: col=o=r16-based, row=c=quad*4+reg)
  // packed: for fixed (mt,nt), r=0..3 -> consecutive e (c&7 in {0..3} or {4..7}) -> one 8B store
#pragma unroll
  for (int mt = 0; mt < 4; ++mt) {
#pragma unroll
    for (int nt = 0; nt < 4; ++nt) {
      const int o = n0 + wn + nt * 16 + r16;
      const int c0 = chalf + wm + mt * 16 + quad * 4;        // r=0 channel; +r consecutive
      const int lane2 = (o & 15) + (((c0 >> 3) & 3) << 4);
      const size_t idx0 = ((size_t)((d * 8 + (c0 >> 5)) * 16 + (o >> 4)) * 512) + lane2 * 8 + (c0 & 7);
      f32x4 v = acc[mt][nt];
      ushort4 w;
      w.x = f2bf(v[0]); w.y = f2bf(v[1]); w.z = f2bf(v[2]); w.w = f2bf(v[3]);
      *(ushort4*)&Bf[idx0] = w;
    }
  }
}

// ---------------- kernel 2: fused pad+convert+implicit-GEMM conv ----------------
__global__ __launch_bounds__(512, 2) void conv_gemm(const float* __restrict__ g,
                                                    const u16* __restrict__ Bf,
                                                    const float* __restrict__ bc,
                                                    float* __restrict__ out) {
  // 2 rotating halo slabs: 6x66 spatial x 32 ch = 1584 chunks x 16B = 25.34 KB each
  __shared__ __align__(16) u16 slab[2][12672];
  const int bid = blockIdx.x;                  // 256 blocks, 1/CU
  const int id2 = ((bid & 7) << 5) | (bid >> 3);  // XCD x -> images 2x, 2x+1
  const int b   = id2 >> 4;                    // image
  const int y0  = (id2 & 15) << 2;             // 4 output y-lines per block (BM=256)

  const int tid  = threadIdx.x;                // 0..511
  const int lane = tid & 63;
  const int wid  = tid >> 6;                   // 0..7
  const int wm   = (wid >> 2) << 7;            // 0 / 128   (2 M-warps)
  const int wn   = (wid & 3) << 6;             // 0/64/128/192 (4 N-warps)
  const int quad = lane >> 4;
  const int r16  = lane & 15;

  // ---- staging setup: chunks k = tid, tid+512, tid+1024, (1536+tid if tid<48).
  // chunk k -> s=k>>2 (spatial row-major in 6x66), slot=k&3; LDS holds source
  // channel-chunk cs = slot ^ ((s>>1)&3) at linear offset k*16B (swizzle identical
  // to R9 so readAh is unchanged). Boundary chunks (padded coords x==0|65, y==0|65)
  // are written as zeros; their pointers are clamped in-bounds and never loaded.
  const bool has3 = (tid < 48);
  int   ldso[4];
  bool  bd[4];
  const float* gsrc[4];
#pragma unroll
  for (int j = 0; j < 4; ++j) {
    const int k = (j < 3) ? (tid + (j << 9)) : (1536 + tid);
    const int s = k >> 2, slot = k & 3;
    const int cs = slot ^ ((s >> 1) & 3);
    const int sy = s / 66, sx = s % 66;
    const int Y  = y0 + sy;                    // padded y coord 0..65
    bd[j] = (sx == 0) | (sx == 65) | (Y == 0) | (Y == 65);
    const int Yc = Y < 1 ? 1 : (Y > 64 ? 64 : Y);
    const int xc = sx < 1 ? 1 : (sx > 64 ? 64 : sx);
    gsrc[j] = g + ((size_t)(((b << 6) + Yc - 1) << 6) + (xc - 1)) * 256 + cs * 8;
    ldso[j] = k * 8;                           // u16 elems
  }

  // B fragment base; per-stage slice stride 8192 elems (kt = d*8 + cb)
  const u16* baseBf = Bf + ((wn >> 4) << 9) + lane * 8;

  const int swm = (wm >> 6) * 66 + r16;        // + K(d,half) -> source spatial s
  const int q8  = quad << 3;                   // quad slot in elems

  // K(d,half) = (half + 1 + oyd)*66 + (1 + oxd); dir order matches Bf (d index)
  // dirs (oxd,oyd): d0(0,1) d1(-1,1) d2(-1,0) d3(-1,-1) d4(0,-1) d5(1,-1) d6(1,0) d7(1,1)
  constexpr int KLO[8] = {133, 132, 66,  0,  1,  2,  68, 134};
  constexpr int KHI[8] = {199, 198, 132, 66, 67, 68, 134, 200};
  // B-load elem offset at sub-phase d: d<=5 -> B(cb,d+2); d=6 -> B(cb+1,0); d=7 -> B(cb+1,1)
  constexpr int LBO[8] = {2 * 65536, 3 * 65536, 4 * 65536, 5 * 65536,
                          6 * 65536, 7 * 65536, 8192, 8192 + 65536};

  f32x4 acc[8][4] = {};
  bf16x8 Be[4], Bo[4];        // B parity regs (even/odd sub-phase)
  bf16x8 afl[4], afh[4];      // A fragment halves (software pipeline)

  auto loadChunk = [&](int j, int cho, float4& a, float4& c) {
    a = make_float4(0.f, 0.f, 0.f, 0.f);
    c = make_float4(0.f, 0.f, 0.f, 0.f);
    if (!bd[j]) {
      a = *(const float4*)(gsrc[j] + cho);
      c = *(const float4*)(gsrc[j] + cho + 4);
    }
  };
  auto writeChunk = [&](u16* bufW, int j, const float4& a, const float4& c) {
    uint4 w;
    w.x = pack2(a.x, a.y); w.y = pack2(a.z, a.w);
    w.z = pack2(c.x, c.y); w.w = pack2(c.z, c.w);
    *(uint4*)&bufW[ldso[j]] = w;
  };
  auto loadB = [&](const u16* pB, int off, bf16x8* dst) {
#pragma unroll
    for (int nt = 0; nt < 4; ++nt) dst[nt] = *(const bf16x8*)(pB + off + nt * 512);
  };
  auto readAh = [&](const u16* bufR, int K, bf16x8* af) {
    const int s  = swm + K;
    const int sw = q8 ^ (((s >> 1) & 3) << 3);
    const u16* p = bufR + s * 32 + sw;
#pragma unroll
    for (int mt = 0; mt < 4; ++mt) af[mt] = *(const bf16x8*)(p + mt * 512);
  };
  auto mfma_half = [&](const bf16x8* af, const bf16x8* bb, int h) {
    __builtin_amdgcn_s_setprio(1);
#pragma unroll
    for (int mt = 0; mt < 4; ++mt)
#pragma unroll
      for (int nt = 0; nt < 4; ++nt)
        acc[h * 4 + mt][nt] =
            __builtin_amdgcn_mfma_f32_16x16x32_bf16(af[mt], bb[nt], acc[h * 4 + mt][nt], 0, 0, 0);
    __builtin_amdgcn_s_setprio(0);
  };
  // one sub-phase: R8 half-split read-ahead (afl holds lo(d), read previously)
  auto subphase = [&](const u16* bufR, const u16* pB, int d, bool nextAfl, bool doB) {
    bf16x8* bu = (d & 1) ? Bo : Be;
    readAh(bufR, KHI[d], afh);                 // hi(d)
    mfma_half(afl, bu, 0);
    if (nextAfl) readAh(bufR, KLO[d + 1], afl); // read-ahead lo(d+1)
    mfma_half(afh, bu, 1);
    if (doB) loadB(pB, LBO[d], bu);            // after mfma: WAR on bu
  };

  // ---- prologue: B(0,0), B(0,1); stage slab[0] (cb=0, cho=0) synchronously ----
  loadB(baseBf, 0, Be);            // B(0,0)  (kt=0)
  loadB(baseBf, 65536, Bo);        // B(0,1)  (kt=8)
  {
    float4 a0, c0, a1, c1, a2, c2, a3, c3;
    loadChunk(0, 0, a0, c0);
    loadChunk(1, 0, a1, c1);
    loadChunk(2, 0, a2, c2);
    if (has3) loadChunk(3, 0, a3, c3);
    writeChunk(slab[0], 0, a0, c0);
    writeChunk(slab[0], 1, a1, c1);
    writeChunk(slab[0], 2, a2, c2);
    if (has3) writeChunk(slab[0], 3, a3, c3);
  }
  asm volatile("s_waitcnt lgkmcnt(0)" ::: "memory");
  asm volatile("s_barrier" ::: "memory");
  readAh(slab[0], KLO[0], afl);    // pre-read lo(d=0) of stage 0

  const u16* pB = baseBf;
  u16* bufR = slab[0];
  u16* bufW = slab[1];
#pragma unroll 1
  for (int cb = 0; cb < 7; ++cb) {
    const int cho = (cb + 1) * 32;             // next stage's channel offset (f32)
    // batch1 issue (chunks 0,1 for cb+1) -- flight spans sub-phases 0..3
    float4 a0, c0, a1, c1;
    loadChunk(0, cho, a0, c0);
    loadChunk(1, cho, a1, c1);
    subphase(bufR, pB, 0, true, true);
    subphase(bufR, pB, 1, true, true);
    subphase(bufR, pB, 2, true, true);
    subphase(bufR, pB, 3, true, true);
    // batch1 write (vmcnt auto: 16 newer B-loads stay flying); batch2 issue
    writeChunk(bufW, 0, a0, c0);
    writeChunk(bufW, 1, a1, c1);
    float4 a2, c2, a3, c3;
    loadChunk(2, cho, a2, c2);
    if (has3) loadChunk(3, cho, a3, c3);
    subphase(bufR, pB, 4, true, true);
    subphase(bufR, pB, 5, true, true);
    subphase(bufR, pB, 6, true, true);
    subphase(bufR, pB, 7, false, true);        // no lo(8); B(cb+1,1) loaded here
    writeChunk(bufW, 2, a2, c2);
    if (has3) writeChunk(bufW, 3, a3, c3);
    asm volatile("s_waitcnt lgkmcnt(0)" ::: "memory");   // ds_writes committed
    asm volatile("s_barrier" ::: "memory");
    readAh(bufW, KLO[0], afl);                 // pre-read lo(0) of next stage
    u16* t = bufR; bufR = bufW; bufW = t;
    pB += 8192;
  }
  // stage 7: no staging, no tail B loads, no end barrier
  subphase(bufR, pB, 0, true, true);           // d<=5 loads B(7,2..7) -- still needed
  subphase(bufR, pB, 1, true, true);
  subphase(bufR, pB, 2, true, true);
  subphase(bufR, pB, 3, true, true);
  subphase(bufR, pB, 4, true, true);
  subphase(bufR, pB, 5, true, true);
  subphase(bufR, pB, 6, true, false);
  subphase(bufR, pB, 7, false, false);

  // epilogue: C/D layout col=lane&15, row=quad*4+reg; block rows = b*4096 + y0*64 + r
  const int pbase = (b * 64 + y0) * 64;
#pragma unroll
  for (int nt = 0; nt < 4; ++nt) {
    const int o = wn + nt * 16 + r16;
    const float bias = bc[o];
#pragma unroll
    for (int mt = 0; mt < 8; ++mt) {
      const int pr = pbase + wm + mt * 16 + quad * 4;
      f32x4 v = acc[mt][nt];
#pragma unroll
      for (int r = 0; r < 4; ++r)
        out[(size_t)(pr + r) * 256 + o] = v[r] + bias;
    }
  }
}

extern "C" void kernel_launch(void* const* d_in, const int* in_sizes, int n_in,
                              void* d_out, int out_size, void* d_ws, size_t ws_size,
                              hipStream_t stream) {
  const float* g  = (const float*)d_in[0];   // [16,64,64,256] f32
  const float* Wd = (const float*)d_in[1];   // [8,256,256]
  const float* Wc = (const float*)d_in[2];   // [256,2048]
  const float* bc = (const float*)d_in[3];   // [256]
  float* out = (float*)d_out;                // [16,64,64,256] f32
  u16* Bf = (u16*)d_ws;                      // 1 MB fragment-ordered weights

  build_mt<<<32, 256, 0, stream>>>(Wd, Wc, Bf);
  conv_gemm<<<256, 512, 0, stream>>>(g, Bf, bc, out);
}

// Round 7
// 252.210 us; speedup vs baseline: 1.1203x; 1.1203x over previous
//
#include <hip/hip_runtime.h>

// DirectionalProcessor: out[b,y,x,o] = bc[o] + sum_{d,c} g[b,y-dy_d,x-dx_d,c] * M_d[c,o]
// with M_d[c,o] = sum_e Wd[d,c,e]*Wc[o,d*256+e]  (folded -> 68.7 GFLOP implicit GEMM
// [65536 x 2048] @ [2048 x 256], B,H,W,C=16,64,64,256, 8 dirs).
//
// R11: R10's fused pad+conv hit the 256 VGPR+AGPR/wave budget (acc 128 AGPR +
// ~160 VGPR demand) and spilled in-loop: WRITE_SIZE 263 MB (output is 64) and
// FETCH 192 MB were scratch traffic, 3x slowdown. Same structure, register diet:
//  (1) staging in 1-chunk batches (8 f32) with 2 alternating named buffers
//      (peak 16 regs, was 32): load j+1 -> write j -> 2 subphases, 4 chunks/stage.
//  (2) no address arrays: int goff[4] (not pointers), boundary bitmask in 1 reg,
//      LDS offsets = tid*8 + compile-time j*4096.
// Demand ~= 128 AGPR + ~110 VGPR < 256 -> no spill. Everything else = R10 (=R9
// schedule): 8 stages x 8 subphases x 32 MFMA, half-split read-ahead, B
// global->reg parity Be/Bo, swizzled slab so readAh is conflict-free, manual
// sync only lgkmcnt(0)+s_barrier per stage; compiler's per-register vmcnt
// keeps B prefetches and staged loads flying.

typedef unsigned short u16;
typedef unsigned int u32;
typedef __attribute__((ext_vector_type(8))) short bf16x8;   // 8 x bf16 = 4 VGPRs
typedef __attribute__((ext_vector_type(4))) float f32x4;

__device__ __forceinline__ u16 f2bf(float f) {   // RNE f32->bf16
  u32 u = __float_as_uint(f);
  u32 r = u + 0x7fffu + ((u >> 16) & 1u);
  return (u16)(r >> 16);
}
__device__ __forceinline__ u32 pack2(float a, float b) {
  return (u32)f2bf(a) | ((u32)f2bf(b) << 16);
}

// ---------------- kernel 1: MFMA weight fold into fragment-ordered Bf ----------------
// Bf u16 index: ((d*8 + c32)*16 + o16)*512 + lane*8 + e, where lane = (o&15) + ((c>>3)&3)*16
// holds M_d[c = c32*32 + (lane>>4)*8 + e][o = o16*16 + (lane&15)]  (B-operand frag order).
__global__ __launch_bounds__(256) void build_mt(const float* __restrict__ Wd,
                                                const float* __restrict__ Wc,
                                                u16* __restrict__ Bf) {
  __shared__ __align__(16) u16 As[128 * 32];
  __shared__ __align__(16) u16 Bs[128 * 32];
  const int bid = blockIdx.x;          // 32 blocks: 2 n-tiles x (8 d x 2 c-halves)
  const int n0    = (bid & 1) << 7;
  const int mblk  = bid >> 1;          // 0..15
  const int d     = mblk >> 1;
  const int chalf = (mblk & 1) << 7;
  const int tid  = threadIdx.x;
  const int lane = tid & 63, wid = tid >> 6;
  const int wm = (wid >> 1) << 6, wn = (wid & 1) << 6;
  const int quad = lane >> 4, r16 = lane & 15;
  const int srow = tid >> 1, hh = tid & 1;
  const int swz  = (srow >> 1) & 3;
  const int ssl  = (quad ^ ((r16 >> 1) & 3)) << 3;
  f32x4 acc[4][4] = {};

  for (int e0 = 0; e0 < 256; e0 += 32) {
    __syncthreads();
    const float* pa = Wd + (size_t)(d * 256 + chalf + srow) * 256 + e0 + hh * 16;
    const float* pb = Wc + (size_t)(n0 + srow) * 2048 + d * 256 + e0 + hh * 16;
#pragma unroll
    for (int i = 0; i < 2; ++i) {
      float4 a0 = *(const float4*)(pa + i * 8);
      float4 a1 = *(const float4*)(pa + i * 8 + 4);
      float4 b0 = *(const float4*)(pb + i * 8);
      float4 b1 = *(const float4*)(pb + i * 8 + 4);
      uint4 va, vb;
      va.x = pack2(a0.x, a0.y); va.y = pack2(a0.z, a0.w);
      va.z = pack2(a1.x, a1.y); va.w = pack2(a1.z, a1.w);
      vb.x = pack2(b0.x, b0.y); vb.y = pack2(b0.z, b0.w);
      vb.z = pack2(b1.x, b1.y); vb.w = pack2(b1.z, b1.w);
      int slot = (2 * hh + i) ^ swz;
      *(uint4*)&As[srow * 32 + slot * 8] = va;
      *(uint4*)&Bs[srow * 32 + slot * 8] = vb;
    }
    __syncthreads();
    bf16x8 bfr[4];
#pragma unroll
    for (int nt = 0; nt < 4; ++nt)
      bfr[nt] = *(const bf16x8*)&Bs[(wn + nt * 16 + r16) * 32 + ssl];
#pragma unroll
    for (int mt = 0; mt < 4; ++mt) {
      bf16x8 af = *(const bf16x8*)&As[(wm + mt * 16 + r16) * 32 + ssl];
#pragma unroll
      for (int nt = 0; nt < 4; ++nt)
        acc[mt][nt] = __builtin_amdgcn_mfma_f32_16x16x32_bf16(af, bfr[nt], acc[mt][nt], 0, 0, 0);
    }
  }
  // scatter into fragment-ordered Bf (C/D layout: col=o=r16-based, row=c=quad*4+reg)
  // packed: for fixed (mt,nt), r=0..3 -> consecutive e -> one 8B store
#pragma unroll
  for (int mt = 0; mt < 4; ++mt) {
#pragma unroll
    for (int nt = 0; nt < 4; ++nt) {
      const int o = n0 + wn + nt * 16 + r16;
      const int c0 = chalf + wm + mt * 16 + quad * 4;        // r=0 channel; +r consecutive
      const int lane2 = (o & 15) + (((c0 >> 3) & 3) << 4);
      const size_t idx0 = ((size_t)((d * 8 + (c0 >> 5)) * 16 + (o >> 4)) * 512) + lane2 * 8 + (c0 & 7);
      f32x4 v = acc[mt][nt];
      ushort4 w;
      w.x = f2bf(v[0]); w.y = f2bf(v[1]); w.z = f2bf(v[2]); w.w = f2bf(v[3]);
      *(ushort4*)&Bf[idx0] = w;
    }
  }
}

// ---------------- kernel 2: fused pad+convert+implicit-GEMM conv ----------------
__global__ __launch_bounds__(512, 2) void conv_gemm(const float* __restrict__ g,
                                                    const u16* __restrict__ Bf,
                                                    const float* __restrict__ bc,
                                                    float* __restrict__ out) {
  // 2 rotating halo slabs: 6x66 spatial x 32 ch = 1584 chunks x 16B = 25.34 KB each
  __shared__ __align__(16) u16 slab[2][12672];
  const int bid = blockIdx.x;                  // 256 blocks, 1/CU
  const int id2 = ((bid & 7) << 5) | (bid >> 3);  // XCD x -> images 2x, 2x+1
  const int b   = id2 >> 4;                    // image
  const int y0  = (id2 & 15) << 2;             // 4 output y-lines per block (BM=256)

  const int tid  = threadIdx.x;                // 0..511
  const int lane = tid & 63;
  const int wid  = tid >> 6;                   // 0..7
  const int wm   = (wid >> 2) << 7;            // 0 / 128   (2 M-warps)
  const int wn   = (wid & 3) << 6;             // 0/64/128/192 (4 N-warps)
  const int quad = lane >> 4;
  const int r16  = lane & 15;

  // ---- staging setup: chunks k = tid + j*512 (j<3), 1536+tid (j==3, tid<48).
  // chunk k -> s=k>>2 (spatial row-major in 6x66), slot=k&3; LDS holds source
  // channel-chunk cs = slot ^ ((s>>1)&3) at linear elem offset k*8 = tid*8 +
  // {0,4096,8192,12288}[j] (compile-time). Boundary chunks (x==0|65, Y==0|65)
  // write zeros; offsets clamped in-bounds, loads skipped.
  const bool has3 = (tid < 48);
  int goff[4];                                 // g elem offsets (loop-invariant)
  u32 bdm = 0;                                 // boundary bitmask
#pragma unroll
  for (int j = 0; j < 4; ++j) {
    const int k = (j < 3) ? (tid + (j << 9)) : (1536 + tid);
    const int s = k >> 2, slot = k & 3;
    const int cs = slot ^ ((s >> 1) & 3);
    const int sy = s / 66, sx = s % 66;
    const int Y  = y0 + sy;                    // padded y coord
    if ((sx == 0) | (sx == 65) | (Y == 0) | (Y == 65)) bdm |= (1u << j);
    const int Yc = Y < 1 ? 1 : (Y > 64 ? 64 : Y);
    const int xc = sx < 1 ? 1 : (sx > 64 ? 64 : sx);
    goff[j] = ((((b << 6) + Yc - 1) << 6) + (xc - 1)) * 256 + cs * 8;
  }
  const int lbase = tid * 8;                   // LDS elem base for chunk writes

  // B fragment base; per-stage slice stride 8192 elems (kt = d*8 + cb)
  const u16* baseBf = Bf + ((wn >> 4) << 9) + lane * 8;

  const int swm = (wm >> 6) * 66 + r16;        // + K(d,half) -> source spatial s
  const int q8  = quad << 3;                   // quad slot in elems

  // K(d,half) = (half + 1 + oyd)*66 + (1 + oxd); dir order matches Bf (d index)
  // dirs (oxd,oyd): d0(0,1) d1(-1,1) d2(-1,0) d3(-1,-1) d4(0,-1) d5(1,-1) d6(1,0) d7(1,1)
  constexpr int KLO[8] = {133, 132, 66,  0,  1,  2,  68, 134};
  constexpr int KHI[8] = {199, 198, 132, 66, 67, 68, 134, 200};
  // B-load elem offset at sub-phase d: d<=5 -> B(cb,d+2); d=6 -> B(cb+1,0); d=7 -> B(cb+1,1)
  constexpr int LBO[8] = {2 * 65536, 3 * 65536, 4 * 65536, 5 * 65536,
                          6 * 65536, 7 * 65536, 8192, 8192 + 65536};

  f32x4 acc[8][4] = {};
  bf16x8 Be[4], Bo[4];        // B parity regs (even/odd sub-phase)
  bf16x8 afl[4], afh[4];      // A fragment halves (software pipeline)
  float4 sA0, sC0, sA1, sC1;  // 2 alternating 1-chunk staging buffers (16 regs peak)

  auto loadChunk = [&](int j, int cho, float4& a, float4& c) {
    a = make_float4(0.f, 0.f, 0.f, 0.f);
    c = make_float4(0.f, 0.f, 0.f, 0.f);
    if (!((bdm >> j) & 1)) {
      const float* p = g + goff[j] + cho;
      a = *(const float4*)p;
      c = *(const float4*)(p + 4);
    }
  };
  auto writeChunk = [&](u16* bufW, int j, const float4& a, const float4& c) {
    uint4 w;
    w.x = pack2(a.x, a.y); w.y = pack2(a.z, a.w);
    w.z = pack2(c.x, c.y); w.w = pack2(c.z, c.w);
    const int off = (j == 3) ? 12288 : (j << 12);
    *(uint4*)&bufW[lbase + off] = w;
  };
  auto loadB = [&](const u16* pB, int off, bf16x8* dst) {
#pragma unroll
    for (int nt = 0; nt < 4; ++nt) dst[nt] = *(const bf16x8*)(pB + off + nt * 512);
  };
  auto readAh = [&](const u16* bufR, int K, bf16x8* af) {
    const int s  = swm + K;
    const int sw = q8 ^ (((s >> 1) & 3) << 3);
    const u16* p = bufR + s * 32 + sw;
#pragma unroll
    for (int mt = 0; mt < 4; ++mt) af[mt] = *(const bf16x8*)(p + mt * 512);
  };
  auto mfma_half = [&](const bf16x8* af, const bf16x8* bb, int h) {
    __builtin_amdgcn_s_setprio(1);
#pragma unroll
    for (int mt = 0; mt < 4; ++mt)
#pragma unroll
      for (int nt = 0; nt < 4; ++nt)
        acc[h * 4 + mt][nt] =
            __builtin_amdgcn_mfma_f32_16x16x32_bf16(af[mt], bb[nt], acc[h * 4 + mt][nt], 0, 0, 0);
    __builtin_amdgcn_s_setprio(0);
  };
  // one sub-phase: half-split read-ahead (afl holds lo(d), read previously)
  auto subphase = [&](const u16* bufR, const u16* pB, int d, bool nextAfl, bool doB) {
    bf16x8* bu = (d & 1) ? Bo : Be;
    readAh(bufR, KHI[d], afh);                 // hi(d)
    mfma_half(afl, bu, 0);
    if (nextAfl) readAh(bufR, KLO[d + 1], afl); // read-ahead lo(d+1)
    mfma_half(afh, bu, 1);
    if (doB) loadB(pB, LBO[d], bu);            // after mfma: WAR on bu
  };

  // ---- prologue: B(0,0), B(0,1); stage slab[0] (cb=0) in 2-chunk batches ----
  loadB(baseBf, 0, Be);            // B(0,0)  (kt=0)
  loadB(baseBf, 65536, Bo);        // B(0,1)  (kt=8)
  loadChunk(0, 0, sA0, sC0);
  loadChunk(1, 0, sA1, sC1);
  writeChunk(slab[0], 0, sA0, sC0);
  writeChunk(slab[0], 1, sA1, sC1);
  loadChunk(2, 0, sA0, sC0);
  if (has3) loadChunk(3, 0, sA1, sC1);
  writeChunk(slab[0], 2, sA0, sC0);
  if (has3) writeChunk(slab[0], 3, sA1, sC1);
  asm volatile("s_waitcnt lgkmcnt(0)" ::: "memory");
  asm volatile("s_barrier" ::: "memory");
  readAh(slab[0], KLO[0], afl);    // pre-read lo(d=0) of stage 0

  const u16* pB = baseBf;
  u16* bufR = slab[0];
  u16* bufW = slab[1];
#pragma unroll 1
  for (int cb = 0; cb < 7; ++cb) {
    const int cho = (cb + 1) * 32;             // next stage's channel offset (f32 elems)
    // 1-chunk staging pipeline: load j+1 issued before write j (write's vmcnt
    // wait retires only chunk-j regs; newer loads keep flying)
    loadChunk(0, cho, sA0, sC0);
    subphase(bufR, pB, 0, true, true);
    subphase(bufR, pB, 1, true, true);
    loadChunk(1, cho, sA1, sC1);
    writeChunk(bufW, 0, sA0, sC0);
    subphase(bufR, pB, 2, true, true);
    subphase(bufR, pB, 3, true, true);
    loadChunk(2, cho, sA0, sC0);
    writeChunk(bufW, 1, sA1, sC1);
    subphase(bufR, pB, 4, true, true);
    subphase(bufR, pB, 5, true, true);
    if (has3) loadChunk(3, cho, sA1, sC1);
    writeChunk(bufW, 2, sA0, sC0);
    subphase(bufR, pB, 6, true, true);
    subphase(bufR, pB, 7, false, true);        // no lo(8); B(cb+1,1) loaded here
    if (has3) writeChunk(bufW, 3, sA1, sC1);
    asm volatile("s_waitcnt lgkmcnt(0)" ::: "memory");   // ds_writes committed
    asm volatile("s_barrier" ::: "memory");
    readAh(bufW, KLO[0], afl);                 // pre-read lo(0) of next stage
    u16* t = bufR; bufR = bufW; bufW = t;
    pB += 8192;
  }
  // stage 7: no staging, no tail B loads, no end barrier
  subphase(bufR, pB, 0, true, true);           // d<=5 loads B(7,2..7) -- still needed
  subphase(bufR, pB, 1, true, true);
  subphase(bufR, pB, 2, true, true);
  subphase(bufR, pB, 3, true, true);
  subphase(bufR, pB, 4, true, true);
  subphase(bufR, pB, 5, true, true);
  subphase(bufR, pB, 6, true, false);
  subphase(bufR, pB, 7, false, false);

  // epilogue: C/D layout col=lane&15, row=quad*4+reg; block rows = b*4096 + y0*64 + r
  const int pbase = (b * 64 + y0) * 64;
#pragma unroll
  for (int nt = 0; nt < 4; ++nt) {
    const int o = wn + nt * 16 + r16;
    const float bias = bc[o];
#pragma unroll
    for (int mt = 0; mt < 8; ++mt) {
      const int pr = pbase + wm + mt * 16 + quad * 4;
      f32x4 v = acc[mt][nt];
#pragma unroll
      for (int r = 0; r < 4; ++r)
        out[(size_t)(pr + r) * 256 + o] = v[r] + bias;
    }
  }
}

extern "C" void kernel_launch(void* const* d_in, const int* in_sizes, int n_in,
                              void* d_out, int out_size, void* d_ws, size_t ws_size,
                              hipStream_t stream) {
  const float* g  = (const float*)d_in[0];   // [16,64,64,256] f32
  const float* Wd = (const float*)d_in[1];   // [8,256,256]
  const float* Wc = (const float*)d_in[2];   // [256,2048]
  const float* bc = (const float*)d_in[3];   // [256]
  float* out = (float*)d_out;                // [16,64,64,256] f32
  u16* Bf = (u16*)d_ws;                      // 1 MB fragment-ordered weights

  build_mt<<<32, 256, 0, stream>>>(Wd, Wc, Bf);
  conv_gemm<<<256, 512, 0, stream>>>(g, Bf, bc, out);
}

// Round 8
// 171.358 us; speedup vs baseline: 1.6489x; 1.4718x over previous
//
#include <hip/hip_runtime.h>

// DirectionalProcessor: out[b,y,x,o] = bc[o] + sum_{d,c} g[b,y-dy_d,x-dx_d,c] * M_d[c,o]
// with M_d[c,o] = sum_e Wd[d,c,e]*Wc[o,d*256+e]  (folded -> 68.7 GFLOP implicit GEMM
// [65536 x 2048] @ [2048 x 256], B,H,W,C=16,64,64,256, 8 dirs).
//
// R12: kill the spill by halving the accumulator. R10/R11 exceeded the 256
// reg/wave cap (2 waves/SIMD): R11 demand ~285 -> ~29 regs spilled in-loop
// (WRITE 171 MB = 64 out + 107 scratch; VGPR_Count pinned at 128+128 AGPR).
// Now BM=128 (2 y-lines/block, 512 blocks, 2 generations/CU), 8 waves 2Mx4N ->
// wave tile 64x64 -> acc 64 regs. Demand ~= 64 AGPR + ~170 VGPR < 256. Slab is
// 4x66x32ch (16.9 KB x2 = 33.8 KB LDS), 3 staged chunks/thread/stage. Halves of
// the R8 read-ahead pipeline are now mt-pairs {0,1}/{2,3} within the wave's
// single y-line -> one K offset per direction (old KHI was just y-line 2).
// Adjacent y-blocks share halo rows on the same XCD -> repeats are L2 hits.
// Fused-kernel roofline: (104 rd + 64 wr) MB @ 6.3 TB/s ~= 27 us; MFMA floor 8.3.

typedef unsigned short u16;
typedef unsigned int u32;
typedef __attribute__((ext_vector_type(8))) short bf16x8;   // 8 x bf16 = 4 VGPRs
typedef __attribute__((ext_vector_type(4))) float f32x4;

__device__ __forceinline__ u16 f2bf(float f) {   // RNE f32->bf16
  u32 u = __float_as_uint(f);
  u32 r = u + 0x7fffu + ((u >> 16) & 1u);
  return (u16)(r >> 16);
}
__device__ __forceinline__ u32 pack2(float a, float b) {
  return (u32)f2bf(a) | ((u32)f2bf(b) << 16);
}

// ---------------- kernel 1: MFMA weight fold into fragment-ordered Bf ----------------
// Bf u16 index: ((d*8 + c32)*16 + o16)*512 + lane*8 + e, where lane = (o&15) + ((c>>3)&3)*16
// holds M_d[c = c32*32 + (lane>>4)*8 + e][o = o16*16 + (lane&15)]  (B-operand frag order).
__global__ __launch_bounds__(256) void build_mt(const float* __restrict__ Wd,
                                                const float* __restrict__ Wc,
                                                u16* __restrict__ Bf) {
  __shared__ __align__(16) u16 As[128 * 32];
  __shared__ __align__(16) u16 Bs[128 * 32];
  const int bid = blockIdx.x;          // 32 blocks: 2 n-tiles x (8 d x 2 c-halves)
  const int n0    = (bid & 1) << 7;
  const int mblk  = bid >> 1;          // 0..15
  const int d     = mblk >> 1;
  const int chalf = (mblk & 1) << 7;
  const int tid  = threadIdx.x;
  const int lane = tid & 63, wid = tid >> 6;
  const int wm = (wid >> 1) << 6, wn = (wid & 1) << 6;
  const int quad = lane >> 4, r16 = lane & 15;
  const int srow = tid >> 1, hh = tid & 1;
  const int swz  = (srow >> 1) & 3;
  const int ssl  = (quad ^ ((r16 >> 1) & 3)) << 3;
  f32x4 acc[4][4] = {};

  for (int e0 = 0; e0 < 256; e0 += 32) {
    __syncthreads();
    const float* pa = Wd + (size_t)(d * 256 + chalf + srow) * 256 + e0 + hh * 16;
    const float* pb = Wc + (size_t)(n0 + srow) * 2048 + d * 256 + e0 + hh * 16;
#pragma unroll
    for (int i = 0; i < 2; ++i) {
      float4 a0 = *(const float4*)(pa + i * 8);
      float4 a1 = *(const float4*)(pa + i * 8 + 4);
      float4 b0 = *(const float4*)(pb + i * 8);
      float4 b1 = *(const float4*)(pb + i * 8 + 4);
      uint4 va, vb;
      va.x = pack2(a0.x, a0.y); va.y = pack2(a0.z, a0.w);
      va.z = pack2(a1.x, a1.y); va.w = pack2(a1.z, a1.w);
      vb.x = pack2(b0.x, b0.y); vb.y = pack2(b0.z, b0.w);
      vb.z = pack2(b1.x, b1.y); vb.w = pack2(b1.z, b1.w);
      int slot = (2 * hh + i) ^ swz;
      *(uint4*)&As[srow * 32 + slot * 8] = va;
      *(uint4*)&Bs[srow * 32 + slot * 8] = vb;
    }
    __syncthreads();
    bf16x8 bfr[4];
#pragma unroll
    for (int nt = 0; nt < 4; ++nt)
      bfr[nt] = *(const bf16x8*)&Bs[(wn + nt * 16 + r16) * 32 + ssl];
#pragma unroll
    for (int mt = 0; mt < 4; ++mt) {
      bf16x8 af = *(const bf16x8*)&As[(wm + mt * 16 + r16) * 32 + ssl];
#pragma unroll
      for (int nt = 0; nt < 4; ++nt)
        acc[mt][nt] = __builtin_amdgcn_mfma_f32_16x16x32_bf16(af, bfr[nt], acc[mt][nt], 0, 0, 0);
    }
  }
  // scatter into fragment-ordered Bf (C/D layout: col=o=r16-based, row=c=quad*4+reg)
  // packed: for fixed (mt,nt), r=0..3 -> consecutive e -> one 8B store
#pragma unroll
  for (int mt = 0; mt < 4; ++mt) {
#pragma unroll
    for (int nt = 0; nt < 4; ++nt) {
      const int o = n0 + wn + nt * 16 + r16;
      const int c0 = chalf + wm + mt * 16 + quad * 4;        // r=0 channel; +r consecutive
      const int lane2 = (o & 15) + (((c0 >> 3) & 3) << 4);
      const size_t idx0 = ((size_t)((d * 8 + (c0 >> 5)) * 16 + (o >> 4)) * 512) + lane2 * 8 + (c0 & 7);
      f32x4 v = acc[mt][nt];
      ushort4 w;
      w.x = f2bf(v[0]); w.y = f2bf(v[1]); w.z = f2bf(v[2]); w.w = f2bf(v[3]);
      *(ushort4*)&Bf[idx0] = w;
    }
  }
}

// ---------------- kernel 2: fused pad+convert+implicit-GEMM conv ----------------
__global__ __launch_bounds__(512, 2) void conv_gemm(const float* __restrict__ g,
                                                    const u16* __restrict__ Bf,
                                                    const float* __restrict__ bc,
                                                    float* __restrict__ out) {
  // 2 rotating halo slabs: 4x66 spatial x 32 ch = 1056 chunks x 16B = 16.9 KB each
  __shared__ __align__(16) u16 slab[2][8448];
  const int bid = blockIdx.x;                  // 512 blocks, 2 generations/CU
  const int xcd = bid & 7;
  const int idx = bid >> 3;                    // 0..63 within XCD
  const int b   = (xcd << 1) | (idx >> 5);     // 2 images per XCD
  const int y0  = (idx & 31) << 1;             // 2 output y-lines per block (BM=128)

  const int tid  = threadIdx.x;                // 0..511
  const int lane = tid & 63;
  const int wid  = tid >> 6;                   // 0..7
  const int wm   = (wid >> 2) << 6;            // 0 / 64   (2 M-warps = y-line wm>>6)
  const int wn   = (wid & 3) << 6;             // 0/64/128/192 (4 N-warps)
  const int quad = lane >> 4;
  const int r16  = lane & 15;

  // ---- staging setup: chunks k = tid, tid+512, (1024+tid if tid<32).
  // chunk k -> s=k>>2 (spatial row-major in 4x66), slot=k&3; LDS holds source
  // channel-chunk cs = slot ^ ((s>>1)&3) at linear elem offset k*8 = tid*8 +
  // {0,4096,8192}[j]. Boundary chunks (x==0|65, Y==0|65) write zeros; offsets
  // clamped in-bounds, loads exec-masked off.
  const bool has2 = (tid < 32);
  int goff[3];                                 // g elem offsets (loop-invariant)
  u32 bdm = 0;                                 // boundary bitmask
#pragma unroll
  for (int j = 0; j < 3; ++j) {
    const int k = (j < 2) ? (tid + (j << 9)) : (1024 + tid);
    const int s = k >> 2, slot = k & 3;
    const int cs = slot ^ ((s >> 1) & 3);
    const int sy = s / 66, sx = s % 66;
    const int Y  = y0 + sy;                    // padded y coord
    if ((sx == 0) | (sx == 65) | (Y == 0) | (Y == 65)) bdm |= (1u << j);
    const int Yc = Y < 1 ? 1 : (Y > 64 ? 64 : Y);
    const int xc = sx < 1 ? 1 : (sx > 64 ? 64 : sx);
    goff[j] = ((((b << 6) + Yc - 1) << 6) + (xc - 1)) * 256 + cs * 8;
  }
  const int lbase = tid * 8;                   // LDS elem base for chunk writes

  // B fragment base; per-stage slice stride 8192 elems (kt = d*8 + cb)
  const u16* baseBf = Bf + ((wn >> 4) << 9) + lane * 8;

  const int swm = (wm >> 6) * 66 + r16;        // + K[d] -> source spatial s
  const int q8  = quad << 3;                   // quad slot in elems

  // K[d] = (1 + oyd)*66 + (1 + oxd); dir order matches Bf (d index)
  // dirs (oxd,oyd): d0(0,1) d1(-1,1) d2(-1,0) d3(-1,-1) d4(0,-1) d5(1,-1) d6(1,0) d7(1,1)
  constexpr int K[8] = {133, 132, 66, 0, 1, 2, 68, 134};
  // B-load elem offset at sub-phase d: d<=5 -> B(cb,d+2); d=6 -> B(cb+1,0); d=7 -> B(cb+1,1)
  constexpr int LBO[8] = {2 * 65536, 3 * 65536, 4 * 65536, 5 * 65536,
                          6 * 65536, 7 * 65536, 8192, 8192 + 65536};

  f32x4 acc[4][4] = {};       // 64 regs: 4 M-frags (x = mt*16+...) x 4 N-frags
  bf16x8 Be[4], Bo[4];        // B parity regs (even/odd sub-phase)
  bf16x8 afl[2], afh[2];      // A fragment halves: mt {0,1} / {2,3}
  float4 sA0, sC0, sA1, sC1;  // 2 alternating 1-chunk staging buffers

  auto loadChunk = [&](int j, int cho, float4& a, float4& c) {
    a = make_float4(0.f, 0.f, 0.f, 0.f);
    c = make_float4(0.f, 0.f, 0.f, 0.f);
    if (!((bdm >> j) & 1)) {
      const float* p = g + goff[j] + cho;
      a = *(const float4*)p;
      c = *(const float4*)(p + 4);
    }
  };
  auto writeChunk = [&](u16* bufW, int j, const float4& a, const float4& c) {
    uint4 w;
    w.x = pack2(a.x, a.y); w.y = pack2(a.z, a.w);
    w.z = pack2(c.x, c.y); w.w = pack2(c.z, c.w);
    const int off = (j == 2) ? 8192 : (j << 12);
    *(uint4*)&bufW[lbase + off] = w;
  };
  auto loadB = [&](const u16* pB, int off, bf16x8* dst) {
#pragma unroll
    for (int nt = 0; nt < 4; ++nt) dst[nt] = *(const bf16x8*)(pB + off + nt * 512);
  };
  auto readAh = [&](const u16* bufR, int Kd, int mtb, bf16x8* af) {
    const int s  = swm + Kd;
    const int sw = q8 ^ (((s >> 1) & 3) << 3);
    const u16* p = bufR + s * 32 + sw + mtb * 512;
    af[0] = *(const bf16x8*)p;
    af[1] = *(const bf16x8*)(p + 512);
  };
  auto mfma_half = [&](const bf16x8* af, const bf16x8* bb, int mtb) {
    __builtin_amdgcn_s_setprio(1);
#pragma unroll
    for (int i = 0; i < 2; ++i)
#pragma unroll
      for (int nt = 0; nt < 4; ++nt)
        acc[mtb + i][nt] =
            __builtin_amdgcn_mfma_f32_16x16x32_bf16(af[i], bb[nt], acc[mtb + i][nt], 0, 0, 0);
    __builtin_amdgcn_s_setprio(0);
  };
  // one sub-phase: half-split read-ahead (afl holds lo(d) = mt{0,1}, read previously)
  auto subphase = [&](const u16* bufR, const u16* pB, int d, bool nextAfl, bool doB) {
    bf16x8* bu = (d & 1) ? Bo : Be;
    readAh(bufR, K[d], 2, afh);                // hi(d) = mt{2,3}
    mfma_half(afl, bu, 0);
    if (nextAfl) readAh(bufR, K[d + 1], 0, afl); // read-ahead lo(d+1)
    mfma_half(afh, bu, 2);
    if (doB) loadB(pB, LBO[d], bu);            // after mfma: WAR on bu
  };

  // ---- prologue: B(0,0), B(0,1); stage slab[0] (cb=0) ----
  loadB(baseBf, 0, Be);            // B(0,0)  (kt=0)
  loadB(baseBf, 65536, Bo);        // B(0,1)  (kt=8)
  loadChunk(0, 0, sA0, sC0);
  loadChunk(1, 0, sA1, sC1);
  writeChunk(slab[0], 0, sA0, sC0);
  writeChunk(slab[0], 1, sA1, sC1);
  if (has2) {
    loadChunk(2, 0, sA0, sC0);
    writeChunk(slab[0], 2, sA0, sC0);
  }
  asm volatile("s_waitcnt lgkmcnt(0)" ::: "memory");
  asm volatile("s_barrier" ::: "memory");
  readAh(slab[0], K[0], 0, afl);   // pre-read lo(d=0) of stage 0

  const u16* pB = baseBf;
  u16* bufR = slab[0];
  u16* bufW = slab[1];
#pragma unroll 1
  for (int cb = 0; cb < 7; ++cb) {
    const int cho = (cb + 1) * 32;             // next stage's channel offset (f32 elems)
    // 1-chunk staging pipeline: load j+1 issued before write j; write's vmcnt
    // wait retires only chunk-j regs, newer loads keep flying.
    loadChunk(0, cho, sA0, sC0);
    subphase(bufR, pB, 0, true, true);
    subphase(bufR, pB, 1, true, true);
    loadChunk(1, cho, sA1, sC1);
    writeChunk(bufW, 0, sA0, sC0);
    subphase(bufR, pB, 2, true, true);
    subphase(bufR, pB, 3, true, true);
    if (has2) loadChunk(2, cho, sA0, sC0);
    writeChunk(bufW, 1, sA1, sC1);
    subphase(bufR, pB, 4, true, true);
    subphase(bufR, pB, 5, true, true);
    if (has2) writeChunk(bufW, 2, sA0, sC0);
    subphase(bufR, pB, 6, true, true);
    subphase(bufR, pB, 7, false, true);        // no lo(8); B(cb+1,1) loaded here
    asm volatile("s_waitcnt lgkmcnt(0)" ::: "memory");   // ds_writes committed
    asm volatile("s_barrier" ::: "memory");
    readAh(bufW, K[0], 0, afl);                // pre-read lo(0) of next stage
    u16* t = bufR; bufR = bufW; bufW = t;
    pB += 8192;
  }
  // stage 7: no staging, no tail B loads, no end barrier
  subphase(bufR, pB, 0, true, true);           // d<=5 loads B(7,2..7) -- still needed
  subphase(bufR, pB, 1, true, true);
  subphase(bufR, pB, 2, true, true);
  subphase(bufR, pB, 3, true, true);
  subphase(bufR, pB, 4, true, true);
  subphase(bufR, pB, 5, true, true);
  subphase(bufR, pB, 6, true, false);
  subphase(bufR, pB, 7, false, false);

  // epilogue: C/D layout col=lane&15, row=quad*4+reg
  // out pixel = b*4096 + (y0 + (wm>>6))*64 + (mt*16 + quad*4 + r)
  const int pbase = (((b << 6) + y0 + (wm >> 6)) << 6);
#pragma unroll
  for (int nt = 0; nt < 4; ++nt) {
    const int o = wn + nt * 16 + r16;
    const float bias = bc[o];
#pragma unroll
    for (int mt = 0; mt < 4; ++mt) {
      const int pr = pbase + mt * 16 + quad * 4;
      f32x4 v = acc[mt][nt];
#pragma unroll
      for (int r = 0; r < 4; ++r)
        out[(size_t)(pr + r) * 256 + o] = v[r] + bias;
    }
  }
}

extern "C" void kernel_launch(void* const* d_in, const int* in_sizes, int n_in,
                              void* d_out, int out_size, void* d_ws, size_t ws_size,
                              hipStream_t stream) {
  const float* g  = (const float*)d_in[0];   // [16,64,64,256] f32
  const float* Wd = (const float*)d_in[1];   // [8,256,256]
  const float* Wc = (const float*)d_in[2];   // [256,2048]
  const float* bc = (const float*)d_in[3];   // [256]
  float* out = (float*)d_out;                // [16,64,64,256] f32
  u16* Bf = (u16*)d_ws;                      // 1 MB fragment-ordered weights

  build_mt<<<32, 256, 0, stream>>>(Wd, Wc, Bf);
  conv_gemm<<<512, 512, 0, stream>>>(g, Bf, bc, out);
}